// Round 2
// baseline (471.894 us; speedup 1.0000x reference)
//
#include <hip/hip_runtime.h>

// WordSAGE: 2-layer bipartite SAGEConv + MLP head.
// Float inputs may be fp32 OR bf16 (harness ambiguity) -> runtime-detected flag
// in ws; dtype-dependent kernels are dual-launched with a flag guard.

#define NG 2500
#define NT 20000
#define NE 640000
#define SRCD 128
#define DSTD 500
#define HID 128
#define NCLS 16
#define RPB 16

typedef unsigned short u16;
typedef unsigned int u32;

__device__ __forceinline__ float b2f(u16 u) { return __uint_as_float(((u32)u) << 16); }
__device__ __forceinline__ float blo(u32 p) { return __uint_as_float(p << 16); }
__device__ __forceinline__ float bhi(u32 p) { return __uint_as_float(p & 0xffff0000u); }
__device__ __forceinline__ u16 f2b(float f) {
    u32 u = __float_as_uint(f);
    u32 r = (u + 0x7fffu + ((u >> 16) & 1u)) >> 16;
    return (u16)r;
}

// ---- dtype detector: flag=1 if bf16-packed, 0 if fp32 ---------------------
// Low u16 of each word, viewed as bf16, has exponent in normal N(0,1) range
// (~[100,140]) almost always when data is bf16; ~16% when fp32 mantissa bits.
__global__ void k_detect(const u32* __restrict__ graw, int* __restrict__ flag) {
    __shared__ int cnt_s;
    if (threadIdx.x == 0) cnt_s = 0;
    __syncthreads();
    int hits = 0;
    for (int i = threadIdx.x; i < 1024; i += 256) {
        u32 e = (graw[i] >> 7) & 0xFFu;
        if (e >= 100u && e <= 140u) hits++;
    }
    atomicAdd(&cnt_s, hits);
    __syncthreads();
    if (threadIdx.x == 0) flag[0] = (cnt_s > 512) ? 1 : 0;
}

// ---- up-convert small tensors to fp32 scratch -----------------------------
struct CArgs {
    const void* src[11];
    float* dst[11];
    int n[11];
};

template <int MODE>
__global__ void k_convert(CArgs a, const int* __restrict__ flag) {
    if (flag[0] != MODE) return;
    int t = blockIdx.y;
    int i = blockIdx.x * 256 + threadIdx.x;
    if (i >= a.n[t]) return;
    float v;
    if (MODE == 1) v = b2f(((const u16*)a.src[t])[i]);
    else           v = ((const float*)a.src[t])[i];
    a.dst[t][i] = v;
}

// ---- CSR build ------------------------------------------------------------
__global__ void k_count(const int* __restrict__ dst, int* __restrict__ cnt) {
    int e = blockIdx.x * 256 + threadIdx.x;
    if (e < NE) {
        unsigned d = (unsigned)dst[e];
        if (d < NT) atomicAdd(&cnt[d], 1);
    }
}

__global__ __launch_bounds__(1024) void k_scan(const int* __restrict__ cnt,
                                               int* __restrict__ rowptr,
                                               int* __restrict__ fill) {
    __shared__ int sums[1024];
    const int T = 1024, CH = (NT + T - 1) / T;  // 20
    int t = threadIdx.x;
    int base = t * CH;
    int s = 0;
    for (int i = 0; i < CH; ++i) {
        int idx = base + i;
        if (idx < NT) s += cnt[idx];
    }
    sums[t] = s;
    __syncthreads();
    for (int off = 1; off < T; off <<= 1) {
        int v = (t >= off) ? sums[t - off] : 0;
        __syncthreads();
        sums[t] += v;
        __syncthreads();
    }
    int run = sums[t] - s;  // exclusive
    for (int i = 0; i < CH; ++i) {
        int idx = base + i;
        if (idx < NT) {
            rowptr[idx] = run;
            fill[idx] = run;
            run += cnt[idx];
        }
    }
    if (t == T - 1) rowptr[NT] = sums[T - 1];
}

__global__ void k_fill(const int* __restrict__ src, const int* __restrict__ dst,
                       int* __restrict__ fill, int* __restrict__ csr) {
    int e = blockIdx.x * 256 + threadIdx.x;
    if (e < NE) {
        unsigned d = (unsigned)dst[e];
        if (d < NT) {
            int p = atomicAdd(&fill[d], 1);
            csr[p] = src[e];
        }
    }
}

// ---- gather-mean over fp32-converted gene ---------------------------------
__global__ __launch_bounds__(256) void k_gather(const float* __restrict__ geneF,
                                                const int* __restrict__ rowptr,
                                                const int* __restrict__ csr,
                                                float* __restrict__ agg) {
    int d = blockIdx.x * 2 + (threadIdx.x >> 7);
    int f = threadIdx.x & 127;
    int b = rowptr[d], e = rowptr[d + 1];
    float acc = 0.f;
    for (int j = b; j < e; ++j) {
        unsigned s = (unsigned)csr[j];
        if (s < NG) acc += geneF[s * SRCD + f];
    }
    agg[d * SRCD + f] = (e > b) ? acc / (float)(e - b) : 0.f;
}

// ---- layer1: h1 = relu(train@W1s + agg@W1n + b1) --------------------------
template <int MODE>
__global__ __launch_bounds__(128) void k_layer1(const void* __restrict__ train_raw,
                                                const float* __restrict__ agg,
                                                const float* __restrict__ W1sF,
                                                const float* __restrict__ W1nF,
                                                const float* __restrict__ b1F,
                                                float* __restrict__ h1,
                                                const int* __restrict__ flag) {
    if (flag[0] != MODE) return;
    __shared__ float smem[RPB * DSTD + RPB * SRCD];  // 8000 + 2048 floats
    float* trF = smem;
    float* ag = smem + RPB * DSTD;
    int n = threadIdx.x;
    int row0 = blockIdx.x * RPB;

    if (MODE == 0) {
        const float4* tg4 = (const float4*)((const float*)train_raw + (size_t)row0 * DSTD);
        float4* t4 = (float4*)trF;
        for (int i = n; i < RPB * DSTD / 4; i += 128) t4[i] = tg4[i];
    } else {
        const u32* tg32 = (const u32*)((const u16*)train_raw + (size_t)row0 * DSTD);
        u32* tr32 = (u32*)trF;  // packed bf16 pairs occupy first 16000 B
        for (int i = n; i < RPB * DSTD / 2; i += 128) tr32[i] = tg32[i];
    }
    const float4* ap4 = (const float4*)(agg + (size_t)row0 * SRCD);
    float4* ag4 = (float4*)ag;
    for (int i = n; i < RPB * SRCD / 4; i += 128) ag4[i] = ap4[i];
    __syncthreads();

    float acc[RPB];
    float bias = b1F[n];
#pragma unroll
    for (int r = 0; r < RPB; ++r) acc[r] = bias;

    if (MODE == 0) {
        for (int k = 0; k < DSTD; k += 4) {
            float w0 = W1sF[k * HID + n];
            float w1 = W1sF[(k + 1) * HID + n];
            float w2 = W1sF[(k + 2) * HID + n];
            float w3 = W1sF[(k + 3) * HID + n];
#pragma unroll
            for (int r = 0; r < RPB; ++r) {
                float4 v = *(const float4*)&trF[r * DSTD + k];
                acc[r] += v.x * w0 + v.y * w1 + v.z * w2 + v.w * w3;
            }
        }
    } else {
        const u32* trr = (const u32*)trF;
        for (int k = 0; k < DSTD; k += 2) {
            float w0 = W1sF[k * HID + n];
            float w1 = W1sF[(k + 1) * HID + n];
#pragma unroll
            for (int r = 0; r < RPB; ++r) {
                u32 p = trr[r * (DSTD / 2) + (k >> 1)];
                acc[r] += blo(p) * w0 + bhi(p) * w1;
            }
        }
    }
    for (int k = 0; k < SRCD; k += 4) {
        float w0 = W1nF[k * HID + n];
        float w1 = W1nF[(k + 1) * HID + n];
        float w2 = W1nF[(k + 2) * HID + n];
        float w3 = W1nF[(k + 3) * HID + n];
#pragma unroll
        for (int r = 0; r < RPB; ++r) {
            float4 v = *(const float4*)&ag[r * SRCD + k];
            acc[r] += v.x * w0 + v.y * w1 + v.z * w2 + v.w * w3;
        }
    }
#pragma unroll
    for (int r = 0; r < RPB; ++r) {
        float v = acc[r];
        h1[(size_t)(row0 + r) * HID + n] = v > 0.f ? v : 0.f;
    }
}

// ---- generic fc: out = relu?(A@Wa [+ B@Wb] + bias), K=N=128 ---------------
__global__ __launch_bounds__(128) void k_fc(const float* __restrict__ A,
                                            const float* __restrict__ Wa,
                                            const float* __restrict__ B,
                                            const float* __restrict__ Wb,
                                            const float* __restrict__ bias,
                                            float* __restrict__ outp, int relu) {
    __shared__ float sa[RPB * 128];
    __shared__ float sb[RPB * 128];
    int n = threadIdx.x;
    int row0 = blockIdx.x * RPB;

    const float4* a4 = (const float4*)(A + (size_t)row0 * 128);
    float4* s4 = (float4*)sa;
    for (int i = n; i < RPB * 128 / 4; i += 128) s4[i] = a4[i];
    if (B) {
        const float4* b4 = (const float4*)(B + (size_t)row0 * 128);
        float4* t4 = (float4*)sb;
        for (int i = n; i < RPB * 128 / 4; i += 128) t4[i] = b4[i];
    }
    __syncthreads();

    float acc[RPB];
    float bv = bias[n];
#pragma unroll
    for (int r = 0; r < RPB; ++r) acc[r] = bv;

    for (int k = 0; k < 128; k += 4) {
        float w0 = Wa[k * 128 + n];
        float w1 = Wa[(k + 1) * 128 + n];
        float w2 = Wa[(k + 2) * 128 + n];
        float w3 = Wa[(k + 3) * 128 + n];
#pragma unroll
        for (int r = 0; r < RPB; ++r) {
            float4 v = *(const float4*)&sa[r * 128 + k];
            acc[r] += v.x * w0 + v.y * w1 + v.z * w2 + v.w * w3;
        }
    }
    if (B) {
        for (int k = 0; k < 128; k += 4) {
            float w0 = Wb[k * 128 + n];
            float w1 = Wb[(k + 1) * 128 + n];
            float w2 = Wb[(k + 2) * 128 + n];
            float w3 = Wb[(k + 3) * 128 + n];
#pragma unroll
            for (int r = 0; r < RPB; ++r) {
                float4 v = *(const float4*)&sb[r * 128 + k];
                acc[r] += v.x * w0 + v.y * w1 + v.z * w2 + v.w * w3;
            }
        }
    }
#pragma unroll
    for (int r = 0; r < RPB; ++r) {
        float v = acc[r];
        if (relu) v = v > 0.f ? v : 0.f;
        outp[(size_t)(row0 + r) * 128 + n] = v;
    }
}

// ---- head: out = H@Wc2 + bc2 ----------------------------------------------
template <int MODE>
__global__ __launch_bounds__(256) void k_out(const float* __restrict__ H,
                                             const float* __restrict__ Wc2F,
                                             const float* __restrict__ bc2F,
                                             void* __restrict__ out_raw,
                                             const int* __restrict__ flag) {
    if (flag[0] != MODE) return;
    __shared__ float sh[16 * 132];
    __shared__ float sw[128 * 16];
    int t = threadIdx.x;
    int row0 = blockIdx.x * 16;
    for (int i = t; i < 16 * 128; i += 256) {
        int r = i >> 7, k = i & 127;
        sh[r * 132 + k] = H[(size_t)(row0 + r) * 128 + k];
    }
    for (int i = t; i < 128 * 16; i += 256) sw[i] = Wc2F[i];
    __syncthreads();
    int r = t >> 4, n = t & 15;
    float acc = bc2F[n];
    for (int k = 0; k < 128; ++k) acc += sh[r * 132 + k] * sw[k * 16 + n];
    if (MODE == 1) ((u16*)out_raw)[(size_t)(row0 + r) * NCLS + n] = f2b(acc);
    else           ((float*)out_raw)[(size_t)(row0 + r) * NCLS + n] = acc;
}

extern "C" void kernel_launch(void* const* d_in, const int* in_sizes, int n_in,
                              void* d_out, int out_size, void* d_ws, size_t ws_size,
                              hipStream_t stream) {
    const void* gene = d_in[0];
    const void* train = d_in[1];
    const int* esrc = (const int*)d_in[2];
    const int* edst = (const int*)d_in[3];

    char* ws = (char*)d_ws;
    int* flag = (int*)(ws + 0);
    int* cnt = (int*)(ws + 64);
    int* rowptr = (int*)(ws + 80064);
    int* fill = (int*)(ws + 160128);
    int* csr = (int*)(ws + 240128);
    float* agg = (float*)(ws + 2800128);
    float* h1 = (float*)(ws + 13040128);
    float* h2 = (float*)(ws + 23280128);
    float* geneF = (float*)(ws + 33520128);
    float* W1nF = (float*)(ws + 34800128);
    float* W1sF = (float*)(ws + 34865664);
    float* b1F = (float*)(ws + 35121664);
    float* W2nF = (float*)(ws + 35122176);
    float* W2sF = (float*)(ws + 35187712);
    float* b2F = (float*)(ws + 35253248);
    float* Wc1F = (float*)(ws + 35253760);
    float* bc1F = (float*)(ws + 35319296);
    float* Wc2F = (float*)(ws + 35319808);
    float* bc2F = (float*)(ws + 35328000);
    // total ws use ~35.4 MB

    hipMemsetAsync(cnt, 0, NT * sizeof(int), stream);
    k_detect<<<1, 256, 0, stream>>>((const u32*)gene, flag);

    CArgs ca;
    const void* srcs[11] = {gene, d_in[4], d_in[5], d_in[6], d_in[7], d_in[8],
                            d_in[9], d_in[10], d_in[11], d_in[12], d_in[13]};
    float* dsts[11] = {geneF, W1nF, W1sF, b1F, W2nF, W2sF, b2F, Wc1F, bc1F, Wc2F, bc2F};
    int ns[11] = {NG * SRCD, SRCD * HID, DSTD * HID, HID, HID * HID, HID * HID,
                  HID, HID * HID, HID, HID * NCLS, NCLS};
    for (int i = 0; i < 11; ++i) { ca.src[i] = srcs[i]; ca.dst[i] = dsts[i]; ca.n[i] = ns[i]; }
    dim3 cgrid((NG * SRCD + 255) / 256, 11);
    k_convert<0><<<cgrid, 256, 0, stream>>>(ca, flag);
    k_convert<1><<<cgrid, 256, 0, stream>>>(ca, flag);

    k_count<<<(NE + 255) / 256, 256, 0, stream>>>(edst, cnt);
    k_scan<<<1, 1024, 0, stream>>>(cnt, rowptr, fill);
    k_fill<<<(NE + 255) / 256, 256, 0, stream>>>(esrc, edst, fill, csr);
    k_gather<<<NT / 2, 256, 0, stream>>>(geneF, rowptr, csr, agg);

    k_layer1<0><<<NT / RPB, 128, 0, stream>>>(train, agg, W1sF, W1nF, b1F, h1, flag);
    k_layer1<1><<<NT / RPB, 128, 0, stream>>>(train, agg, W1sF, W1nF, b1F, h1, flag);

    k_fc<<<NT / RPB, 128, 0, stream>>>(h1, W2sF, agg, W2nF, b2F, h2, 1);
    k_fc<<<NT / RPB, 128, 0, stream>>>(h2, Wc1F, nullptr, nullptr, bc1F, h1, 1);

    k_out<0><<<NT / 16, 256, 0, stream>>>(h1, Wc2F, bc2F, d_out, flag);
    k_out<1><<<NT / 16, 256, 0, stream>>>(h1, Wc2F, bc2F, d_out, flag);
}

// Round 5
// 438.680 us; speedup vs baseline: 1.0757x; 1.0757x over previous
//
#include <hip/hip_runtime.h>

// WordSAGE on MI355X. Input float dtype is AMBIGUOUS (fp32 per reference
// source vs bf16 per harness label) -> runtime detector writes flag to ws;
// BOTH pipelines are compiled & launched, each guarded by the flag:
//   flag==1 (bf16): CSR -> bf16 gather -> fused 4-layer MFMA mega-kernel
//   flag==0 (fp32): CSR -> fp32 gather -> round-2 VALU pipeline (proven pass)
// Round-3/4 NaN is explained by fp32 data read as bf16 pairs (exp=0xFF
// patterns in mantissa halves), not by the LDS barrier issue.

#define NG 2500
#define NT 20000
#define NE 640000
#define SRCD 128
#define DSTD 500
#define HID 128
#define NCLS 16
#define RPB 16

typedef unsigned short u16;
typedef unsigned int u32;

typedef float f32x4 __attribute__((ext_vector_type(4)));
typedef __bf16 bf16x8 __attribute__((ext_vector_type(8)));

__device__ __forceinline__ float blo(u32 p) { return __uint_as_float(p << 16); }
__device__ __forceinline__ float bhi(u32 p) { return __uint_as_float(p & 0xffff0000u); }
__device__ __forceinline__ float b2f(u16 u) { return __uint_as_float(((u32)u) << 16); }
__device__ __forceinline__ u16 f2b(float f) {
    u32 u = __float_as_uint(f);
    return (u16)((u + 0x7fffu + ((u >> 16) & 1u)) >> 16);
}

// ---- dtype detector: flag=1 if bf16-packed, 0 if fp32 ---------------------
__global__ void k_detect(const u32* __restrict__ graw, int* __restrict__ flag) {
    __shared__ int cnt_s;
    if (threadIdx.x == 0) cnt_s = 0;
    __syncthreads();
    int hits = 0;
    for (int i = threadIdx.x; i < 1024; i += 256) {
        u32 e = (graw[i] >> 7) & 0xFFu;  // low u16 viewed as bf16: exponent
        if (e >= 100u && e <= 140u) hits++;
    }
    atomicAdd(&cnt_s, hits);
    __syncthreads();
    if (threadIdx.x == 0) flag[0] = (cnt_s > 512) ? 1 : 0;
}

// ---- CSR build (dtype-independent) ----------------------------------------
__global__ void k_count(const int* __restrict__ dst, int* __restrict__ cnt) {
    int e = blockIdx.x * 256 + threadIdx.x;
    if (e < NE) {
        unsigned d = (unsigned)dst[e];
        if (d < NT) atomicAdd(&cnt[d], 1);
    }
}

__global__ __launch_bounds__(1024) void k_scan(const int* __restrict__ cnt,
                                               int* __restrict__ rowptr,
                                               int* __restrict__ fill) {
    __shared__ int sums[1024];
    const int T = 1024, CH = (NT + T - 1) / T;  // 20
    int t = threadIdx.x;
    int base = t * CH;
    int s = 0;
    for (int i = 0; i < CH; ++i) {
        int idx = base + i;
        if (idx < NT) s += cnt[idx];
    }
    sums[t] = s;
    __syncthreads();
    for (int off = 1; off < T; off <<= 1) {
        int v = (t >= off) ? sums[t - off] : 0;
        __syncthreads();
        sums[t] += v;
        __syncthreads();
    }
    int run = sums[t] - s;  // exclusive prefix
    for (int i = 0; i < CH; ++i) {
        int idx = base + i;
        if (idx < NT) {
            rowptr[idx] = run;
            fill[idx] = run;
            run += cnt[idx];
        }
    }
    if (t == T - 1) rowptr[NT] = sums[T - 1];
}

__global__ void k_fill(const int* __restrict__ src, const int* __restrict__ dst,
                       int* __restrict__ fill, int* __restrict__ csr) {
    int e = blockIdx.x * 256 + threadIdx.x;
    if (e < NE) {
        unsigned d = (unsigned)dst[e];
        if (d < NT) {
            int p = atomicAdd(&fill[d], 1);
            csr[p] = src[e];
        }
    }
}

// =================== PATH A: bf16 (flag==1) ================================

__global__ __launch_bounds__(256) void k_gather_b(const u32* __restrict__ gene32,
                                                  const int* __restrict__ rowptr,
                                                  const int* __restrict__ csr,
                                                  u32* __restrict__ agg32,
                                                  const int* __restrict__ flag) {
    if (flag[0] != 1) return;
    int wave = threadIdx.x >> 6, lane = threadIdx.x & 63;
    int d = blockIdx.x * 4 + wave;
    int b = rowptr[d], e = rowptr[d + 1];
    float a0 = 0.f, a1 = 0.f;
    for (int j = b; j < e; ++j) {
        unsigned s = (unsigned)csr[j];
        if (s < NG) {
            u32 p = gene32[s * 64 + lane];
            a0 += blo(p);
            a1 += bhi(p);
        }
    }
    float inv = (e > b) ? 1.f / (float)(e - b) : 0.f;
    a0 *= inv; a1 *= inv;
    agg32[(size_t)d * 64 + lane] = (u32)f2b(a0) | ((u32)f2b(a1) << 16);
}

// B-frag for 16x16x32: lane l holds B[k = kk*32 + (l>>4)*8 + j][n = g*16 + (l&15)]
#define B1N 81920   // K=640 (train 0..499, zero 500..511, agg 512..639), N=128
#define B2N 32768   // K=256 (h1 -> W2s, agg -> W2n), N=128
#define B3N 16384   // K=128 Wc1, N=128
#define B4N 2048    // K=128 Wc2, N=16
__global__ void k_pack(const u16* __restrict__ W1n, const u16* __restrict__ W1s,
                       const u16* __restrict__ W2n, const u16* __restrict__ W2s,
                       const u16* __restrict__ Wc1, const u16* __restrict__ Wc2,
                       u16* __restrict__ Bp1, u16* __restrict__ Bp2,
                       u16* __restrict__ Bp3, u16* __restrict__ Bp4,
                       const int* __restrict__ flag) {
    if (flag[0] != 1) return;
    int idx = blockIdx.x * 256 + threadIdx.x;
    if (idx < B1N) {
        int j = idx & 7, l = (idx >> 3) & 63, rest = idx >> 9;
        int g = rest & 7, kk = rest >> 3;
        int k = kk * 32 + ((l >> 4) << 3) + j, n = (g << 4) + (l & 15);
        u16 v = 0;
        if (k < 500) v = W1s[k * 128 + n];
        else if (k >= 512) v = W1n[(k - 512) * 128 + n];
        Bp1[idx] = v;
    } else if (idx < B1N + B2N) {
        int e = idx - B1N;
        int j = e & 7, l = (e >> 3) & 63, rest = e >> 9;
        int g = rest & 7, kk = rest >> 3;
        int k = kk * 32 + ((l >> 4) << 3) + j, n = (g << 4) + (l & 15);
        Bp2[e] = (k < 128) ? W2s[k * 128 + n] : W2n[(k - 128) * 128 + n];
    } else if (idx < B1N + B2N + B3N) {
        int e = idx - (B1N + B2N);
        int j = e & 7, l = (e >> 3) & 63, rest = e >> 9;
        int g = rest & 7, kk = rest >> 3;
        int k = kk * 32 + ((l >> 4) << 3) + j, n = (g << 4) + (l & 15);
        Bp3[e] = Wc1[k * 128 + n];
    } else if (idx < B1N + B2N + B3N + B4N) {
        int e = idx - (B1N + B2N + B3N);
        int j = e & 7, l = (e >> 3) & 63, kk = e >> 9;
        int k = kk * 32 + ((l >> 4) << 3) + j, n = l & 15;
        Bp4[e] = Wc2[k * 16 + n];
    }
}

__global__ __launch_bounds__(256) void k_mega(
    const u16* __restrict__ train, const u16* __restrict__ aggB,
    const u16* __restrict__ Bp1, const u16* __restrict__ Bp2,
    const u16* __restrict__ Bp3, const u16* __restrict__ Bp4,
    const u16* __restrict__ b1, const u16* __restrict__ b2,
    const u16* __restrict__ bc1, const u16* __restrict__ bc2,
    u16* __restrict__ out, const int* __restrict__ flag) {
    if (flag[0] != 1) return;
    __shared__ __align__(16) u16 SA[64 * 648];   // k 0..511 train+pad, 512..639 agg
    __shared__ __align__(16) u16 SH1[64 * 136];
    __shared__ __align__(16) u16 SH2[64 * 136];
    int t = threadIdx.x;
    int row0 = blockIdx.x * 64;

    u32* SA32 = (u32*)SA;
    const u32* tr32 = (const u32*)train;
    for (int i = t; i < 64 * 256; i += 256) {
        int r = i >> 8, c = i & 255;
        int gr = row0 + r;
        u32 v = 0;
        if (c < 250 && gr < NT) v = tr32[(size_t)gr * 250 + c];
        SA32[r * 324 + c] = v;
    }
    const u32* ag32 = (const u32*)aggB;
    for (int i = t; i < 64 * 64; i += 256) {
        int r = i >> 6, c = i & 63;
        int gr = row0 + r;
        u32 v = (gr < NT) ? ag32[(size_t)gr * 64 + c] : 0;
        SA32[r * 324 + 256 + c] = v;
    }
    __syncthreads();

    int lane = t & 63, wave = t >> 6;
    int m = lane & 15, q = lane >> 4;
    int arow = (wave * 16 + m) * 648 + q * 8;
    int hrow = (wave * 16 + m) * 136 + q * 8;
    int crow = wave * 16 + q * 4;
    int n16 = lane & 15;
    const f32x4 z4 = {0.f, 0.f, 0.f, 0.f};

    f32x4 acc[8];
#pragma unroll
    for (int g = 0; g < 8; ++g) acc[g] = z4;
    for (int kk = 0; kk < 20; ++kk) {
        bf16x8 a = *(const bf16x8*)(SA + arow + kk * 32);
        const u16* bp = Bp1 + ((size_t)(kk * 8) * 64 + lane) * 8;
#pragma unroll
        for (int g = 0; g < 8; ++g) {
            bf16x8 b = *(const bf16x8*)(bp + g * 512);
            acc[g] = __builtin_amdgcn_mfma_f32_16x16x32_bf16(a, b, acc[g], 0, 0, 0);
        }
    }
#pragma unroll
    for (int g = 0; g < 8; ++g) {
        int n = g * 16 + n16;
        float bias = b2f(b1[n]);
#pragma unroll
        for (int rg = 0; rg < 4; ++rg) {
            float v = acc[g][rg] + bias;
            v = v > 0.f ? v : 0.f;
            SH1[(crow + rg) * 136 + n] = f2b(v);
        }
    }
    __syncthreads();

#pragma unroll
    for (int g = 0; g < 8; ++g) acc[g] = z4;
    for (int kk = 0; kk < 8; ++kk) {
        bf16x8 a = (kk < 4) ? *(const bf16x8*)(SH1 + hrow + kk * 32)
                            : *(const bf16x8*)(SA + arow + 512 + (kk - 4) * 32);
        const u16* bp = Bp2 + ((size_t)(kk * 8) * 64 + lane) * 8;
#pragma unroll
        for (int g = 0; g < 8; ++g) {
            bf16x8 b = *(const bf16x8*)(bp + g * 512);
            acc[g] = __builtin_amdgcn_mfma_f32_16x16x32_bf16(a, b, acc[g], 0, 0, 0);
        }
    }
#pragma unroll
    for (int g = 0; g < 8; ++g) {
        int n = g * 16 + n16;
        float bias = b2f(b2[n]);
#pragma unroll
        for (int rg = 0; rg < 4; ++rg) {
            float v = acc[g][rg] + bias;
            v = v > 0.f ? v : 0.f;
            SH2[(crow + rg) * 136 + n] = f2b(v);
        }
    }
    __syncthreads();

#pragma unroll
    for (int g = 0; g < 8; ++g) acc[g] = z4;
    for (int kk = 0; kk < 4; ++kk) {
        bf16x8 a = *(const bf16x8*)(SH2 + hrow + kk * 32);
        const u16* bp = Bp3 + ((size_t)(kk * 8) * 64 + lane) * 8;
#pragma unroll
        for (int g = 0; g < 8; ++g) {
            bf16x8 b = *(const bf16x8*)(bp + g * 512);
            acc[g] = __builtin_amdgcn_mfma_f32_16x16x32_bf16(a, b, acc[g], 0, 0, 0);
        }
    }
#pragma unroll
    for (int g = 0; g < 8; ++g) {
        int n = g * 16 + n16;
        float bias = b2f(bc1[n]);
#pragma unroll
        for (int rg = 0; rg < 4; ++rg) {
            float v = acc[g][rg] + bias;
            v = v > 0.f ? v : 0.f;
            SH1[(crow + rg) * 136 + n] = f2b(v);
        }
    }
    __syncthreads();

    f32x4 acc4 = z4;
    for (int kk = 0; kk < 4; ++kk) {
        bf16x8 a = *(const bf16x8*)(SH1 + hrow + kk * 32);
        bf16x8 b = *(const bf16x8*)(Bp4 + ((size_t)kk * 64 + lane) * 8);
        acc4 = __builtin_amdgcn_mfma_f32_16x16x32_bf16(a, b, acc4, 0, 0, 0);
    }
    float bias4 = b2f(bc2[n16]);
    int grow = row0 + crow;
#pragma unroll
    for (int rg = 0; rg < 4; ++rg) {
        int r = grow + rg;
        if (r < NT) out[(size_t)r * NCLS + n16] = f2b(acc4[rg] + bias4);
    }
}

// =================== PATH B: fp32 (flag==0), round-2 proven ================

__global__ __launch_bounds__(256) void k_gather_f(const float* __restrict__ geneF,
                                                  const int* __restrict__ rowptr,
                                                  const int* __restrict__ csr,
                                                  float* __restrict__ aggF,
                                                  const int* __restrict__ flag) {
    if (flag[0] != 0) return;
    int wave = threadIdx.x >> 6, lane = threadIdx.x & 63;
    int d = blockIdx.x * 4 + wave;
    int b = rowptr[d], e = rowptr[d + 1];
    float a0 = 0.f, a1 = 0.f;
    for (int j = b; j < e; ++j) {
        unsigned s = (unsigned)csr[j];
        if (s < NG) {
            const float* gp = geneF + (size_t)s * SRCD + lane * 2;
            a0 += gp[0];
            a1 += gp[1];
        }
    }
    float inv = (e > b) ? 1.f / (float)(e - b) : 0.f;
    aggF[(size_t)d * SRCD + lane * 2] = a0 * inv;
    aggF[(size_t)d * SRCD + lane * 2 + 1] = a1 * inv;
}

__global__ __launch_bounds__(128) void k_layer1_f(const float* __restrict__ trainF,
                                                  const float* __restrict__ aggF,
                                                  const float* __restrict__ W1sF,
                                                  const float* __restrict__ W1nF,
                                                  const float* __restrict__ b1F,
                                                  float* __restrict__ h1,
                                                  const int* __restrict__ flag) {
    if (flag[0] != 0) return;
    __shared__ float smem[RPB * DSTD + RPB * SRCD];
    float* trF = smem;
    float* ag = smem + RPB * DSTD;
    int n = threadIdx.x;
    int row0 = blockIdx.x * RPB;

    const float4* tg4 = (const float4*)(trainF + (size_t)row0 * DSTD);
    float4* t4 = (float4*)trF;
    for (int i = n; i < RPB * DSTD / 4; i += 128) t4[i] = tg4[i];
    const float4* ap4 = (const float4*)(aggF + (size_t)row0 * SRCD);
    float4* ag4 = (float4*)ag;
    for (int i = n; i < RPB * SRCD / 4; i += 128) ag4[i] = ap4[i];
    __syncthreads();

    float acc[RPB];
    float bias = b1F[n];
#pragma unroll
    for (int r = 0; r < RPB; ++r) acc[r] = bias;

    for (int k = 0; k < DSTD; k += 4) {
        float w0 = W1sF[k * HID + n];
        float w1 = W1sF[(k + 1) * HID + n];
        float w2 = W1sF[(k + 2) * HID + n];
        float w3 = W1sF[(k + 3) * HID + n];
#pragma unroll
        for (int r = 0; r < RPB; ++r) {
            float4 v = *(const float4*)&trF[r * DSTD + k];
            acc[r] += v.x * w0 + v.y * w1 + v.z * w2 + v.w * w3;
        }
    }
    for (int k = 0; k < SRCD; k += 4) {
        float w0 = W1nF[k * HID + n];
        float w1 = W1nF[(k + 1) * HID + n];
        float w2 = W1nF[(k + 2) * HID + n];
        float w3 = W1nF[(k + 3) * HID + n];
#pragma unroll
        for (int r = 0; r < RPB; ++r) {
            float4 v = *(const float4*)&ag[r * SRCD + k];
            acc[r] += v.x * w0 + v.y * w1 + v.z * w2 + v.w * w3;
        }
    }
#pragma unroll
    for (int r = 0; r < RPB; ++r) {
        float v = acc[r];
        h1[(size_t)(row0 + r) * HID + n] = v > 0.f ? v : 0.f;
    }
}

__global__ __launch_bounds__(128) void k_fc(const float* __restrict__ A,
                                            const float* __restrict__ Wa,
                                            const float* __restrict__ B,
                                            const float* __restrict__ Wb,
                                            const float* __restrict__ bias,
                                            float* __restrict__ outp, int relu,
                                            const int* __restrict__ flag) {
    if (flag[0] != 0) return;
    __shared__ float sa[RPB * 128];
    __shared__ float sb[RPB * 128];
    int n = threadIdx.x;
    int row0 = blockIdx.x * RPB;

    const float4* a4 = (const float4*)(A + (size_t)row0 * 128);
    float4* s4 = (float4*)sa;
    for (int i = n; i < RPB * 128 / 4; i += 128) s4[i] = a4[i];
    if (B) {
        const float4* b4 = (const float4*)(B + (size_t)row0 * 128);
        float4* t4 = (float4*)sb;
        for (int i = n; i < RPB * 128 / 4; i += 128) t4[i] = b4[i];
    }
    __syncthreads();

    float acc[RPB];
    float bv = bias[n];
#pragma unroll
    for (int r = 0; r < RPB; ++r) acc[r] = bv;

    for (int k = 0; k < 128; k += 4) {
        float w0 = Wa[k * 128 + n];
        float w1 = Wa[(k + 1) * 128 + n];
        float w2 = Wa[(k + 2) * 128 + n];
        float w3 = Wa[(k + 3) * 128 + n];
#pragma unroll
        for (int r = 0; r < RPB; ++r) {
            float4 v = *(const float4*)&sa[r * 128 + k];
            acc[r] += v.x * w0 + v.y * w1 + v.z * w2 + v.w * w3;
        }
    }
    if (B) {
        for (int k = 0; k < 128; k += 4) {
            float w0 = Wb[k * 128 + n];
            float w1 = Wb[(k + 1) * 128 + n];
            float w2 = Wb[(k + 2) * 128 + n];
            float w3 = Wb[(k + 3) * 128 + n];
#pragma unroll
            for (int r = 0; r < RPB; ++r) {
                float4 v = *(const float4*)&sb[r * 128 + k];
                acc[r] += v.x * w0 + v.y * w1 + v.z * w2 + v.w * w3;
            }
        }
    }
#pragma unroll
    for (int r = 0; r < RPB; ++r) {
        float v = acc[r];
        if (relu) v = v > 0.f ? v : 0.f;
        outp[(size_t)(row0 + r) * 128 + n] = v;
    }
}

__global__ __launch_bounds__(256) void k_out_f(const float* __restrict__ H,
                                               const float* __restrict__ Wc2F,
                                               const float* __restrict__ bc2F,
                                               float* __restrict__ outp,
                                               const int* __restrict__ flag) {
    if (flag[0] != 0) return;
    __shared__ float sh[16 * 132];
    __shared__ float sw[128 * 16];
    int t = threadIdx.x;
    int row0 = blockIdx.x * 16;
    for (int i = t; i < 16 * 128; i += 256) {
        int r = i >> 7, k = i & 127;
        sh[r * 132 + k] = H[(size_t)(row0 + r) * 128 + k];
    }
    for (int i = t; i < 128 * 16; i += 256) sw[i] = Wc2F[i];
    __syncthreads();
    int r = t >> 4, n = t & 15;
    float acc = bc2F[n];
    for (int k = 0; k < 128; ++k) acc += sh[r * 132 + k] * sw[k * 16 + n];
    outp[(size_t)(row0 + r) * NCLS + n] = acc;
}

extern "C" void kernel_launch(void* const* d_in, const int* in_sizes, int n_in,
                              void* d_out, int out_size, void* d_ws, size_t ws_size,
                              hipStream_t stream) {
    const void* gene = d_in[0];
    const void* train = d_in[1];
    const int* esrc = (const int*)d_in[2];
    const int* edst = (const int*)d_in[3];

    char* ws = (char*)d_ws;
    int* flag = (int*)(ws + 0);
    int* cnt = (int*)(ws + 64);           // 80000
    int* rowptr = (int*)(ws + 80064);     // 80004
    int* fill = (int*)(ws + 160128);      // 80000
    int* csr = (int*)(ws + 240128);       // 2560000
    // union region @2800128:
    //  path B: aggF 10.24MB | h1 10.24MB | h2 10.24MB  (end 33.5MB)
    //  path A: aggB 5.12MB  | Bp1..4 ~266KB            (end  8.2MB)
    float* aggF = (float*)(ws + 2800128);
    float* h1 = (float*)(ws + 13040128);
    float* h2 = (float*)(ws + 23280128);
    u16* aggB = (u16*)(ws + 2800128);
    u16* Bp1 = (u16*)(ws + 7920128);
    u16* Bp2 = (u16*)(ws + 8083968);
    u16* Bp3 = (u16*)(ws + 8149504);
    u16* Bp4 = (u16*)(ws + 8182272);

    hipMemsetAsync(cnt, 0, NT * sizeof(int), stream);
    k_detect<<<1, 256, 0, stream>>>((const u32*)gene, flag);

    k_count<<<(NE + 255) / 256, 256, 0, stream>>>(edst, cnt);
    k_scan<<<1, 1024, 0, stream>>>(cnt, rowptr, fill);
    k_fill<<<(NE + 255) / 256, 256, 0, stream>>>(esrc, edst, fill, csr);

    // ---- path A (bf16) ----
    k_gather_b<<<NT / 4, 256, 0, stream>>>((const u32*)gene, rowptr, csr,
                                           (u32*)aggB, flag);
    k_pack<<<(B1N + B2N + B3N + B4N) / 256, 256, 0, stream>>>(
        (const u16*)d_in[4], (const u16*)d_in[5], (const u16*)d_in[7],
        (const u16*)d_in[8], (const u16*)d_in[10], (const u16*)d_in[12],
        Bp1, Bp2, Bp3, Bp4, flag);
    k_mega<<<(NT + 63) / 64, 256, 0, stream>>>(
        (const u16*)train, aggB, Bp1, Bp2, Bp3, Bp4,
        (const u16*)d_in[6], (const u16*)d_in[9], (const u16*)d_in[11],
        (const u16*)d_in[13], (u16*)d_out, flag);

    // ---- path B (fp32) ----
    k_gather_f<<<NT / 4, 256, 0, stream>>>((const float*)gene, rowptr, csr,
                                           aggF, flag);
    k_layer1_f<<<NT / RPB, 128, 0, stream>>>((const float*)train, aggF,
                                             (const float*)d_in[5],
                                             (const float*)d_in[4],
                                             (const float*)d_in[6], h1, flag);
    k_fc<<<NT / RPB, 128, 0, stream>>>(h1, (const float*)d_in[8], aggF,
                                       (const float*)d_in[7],
                                       (const float*)d_in[9], h2, 1, flag);
    k_fc<<<NT / RPB, 128, 0, stream>>>(h2, (const float*)d_in[10], nullptr,
                                       nullptr, (const float*)d_in[11], h1, 1, flag);
    k_out_f<<<NT / 16, 256, 0, stream>>>(h1, (const float*)d_in[12],
                                         (const float*)d_in[13],
                                         (float*)d_out, flag);
}

// Round 6
// 290.669 us; speedup vs baseline: 1.6235x; 1.5092x over previous
//
#include <hip/hip_runtime.h>

// WordSAGE on MI355X — fp32 inputs/outputs (proven round 5: path-B live).
// Pipeline: CSR build -> float2 gather-mean -> fused 4-layer GEMM stack using
// split-precision bf16 MFMA (x = hi + lo bf16; D = Ah*Bh + Ah*Bl + Al*Bh;
// dropped Al*Bl term ~2^-18 rel). Error budget ~1e-4 vs 3.2e-2 threshold.

#define NG 2500
#define NT 20000
#define NE 640000
#define NCLS 16

typedef unsigned short u16;
typedef unsigned int u32;

typedef float f32x4 __attribute__((ext_vector_type(4)));
typedef __bf16 bf16x8 __attribute__((ext_vector_type(8)));

__device__ __forceinline__ float b2f(u16 u) { return __uint_as_float(((u32)u) << 16); }
__device__ __forceinline__ u16 f2b(float f) {  // RNE fp32->bf16
    u32 u = __float_as_uint(f);
    return (u16)((u + 0x7fffu + ((u >> 16) & 1u)) >> 16);
}

// ---- CSR build ------------------------------------------------------------
__global__ void k_count(const int* __restrict__ dst, int* __restrict__ cnt) {
    int e = blockIdx.x * 256 + threadIdx.x;
    if (e < NE) {
        unsigned d = (unsigned)dst[e];
        if (d < NT) atomicAdd(&cnt[d], 1);
    }
}

__global__ __launch_bounds__(1024) void k_scan(const int* __restrict__ cnt,
                                               int* __restrict__ rowptr,
                                               int* __restrict__ fill) {
    __shared__ int sums[1024];
    const int T = 1024, CH = (NT + T - 1) / T;  // 20
    int t = threadIdx.x;
    int base = t * CH;
    int s = 0;
    for (int i = 0; i < CH; ++i) {
        int idx = base + i;
        if (idx < NT) s += cnt[idx];
    }
    sums[t] = s;
    __syncthreads();
    for (int off = 1; off < T; off <<= 1) {
        int v = (t >= off) ? sums[t - off] : 0;
        __syncthreads();
        sums[t] += v;
        __syncthreads();
    }
    int run = sums[t] - s;  // exclusive prefix
    for (int i = 0; i < CH; ++i) {
        int idx = base + i;
        if (idx < NT) {
            rowptr[idx] = run;
            fill[idx] = run;
            run += cnt[idx];
        }
    }
    if (t == T - 1) rowptr[NT] = sums[T - 1];
}

__global__ void k_fill(const int* __restrict__ src, const int* __restrict__ dst,
                       int* __restrict__ fill, int* __restrict__ csr) {
    int e = blockIdx.x * 256 + threadIdx.x;
    if (e < NE) {
        unsigned d = (unsigned)dst[e];
        if (d < NT) {
            int p = atomicAdd(&fill[d], 1);
            csr[p] = src[e];
        }
    }
}

// ---- gather-mean: fp32 gene -> fp32 agg, float2 per lane ------------------
__global__ __launch_bounds__(256) void k_gather(const float2* __restrict__ g2,
                                                const int* __restrict__ rowptr,
                                                const int* __restrict__ csr,
                                                float2* __restrict__ agg2) {
    int wave = threadIdx.x >> 6, lane = threadIdx.x & 63;
    int d = blockIdx.x * 4 + wave;
    int b = rowptr[d], e = rowptr[d + 1];
    float a0 = 0.f, a1 = 0.f, c0 = 0.f, c1 = 0.f;
    int j = b;
    for (; j + 1 < e; j += 2) {
        int s0 = csr[j], s1 = csr[j + 1];
        float2 v0 = g2[(size_t)s0 * 64 + lane];
        float2 v1 = g2[(size_t)s1 * 64 + lane];
        a0 += v0.x; a1 += v0.y;
        c0 += v1.x; c1 += v1.y;
    }
    if (j < e) {
        int s = csr[j];
        float2 v = g2[(size_t)s * 64 + lane];
        a0 += v.x; a1 += v.y;
    }
    float inv = (e > b) ? 1.f / (float)(e - b) : 0.f;
    float2 r;
    r.x = (a0 + c0) * inv;
    r.y = (a1 + c1) * inv;
    agg2[(size_t)d * 64 + lane] = r;
}

// ---- pack fp32 weights into split hi/lo bf16 B-fragment buffers -----------
// B-frag (16x16x32): lane l holds B[k = kk*32 + (l>>4)*8 + j][n = g*16 + (l&15)],
// memory idx = (((kk*gN + g)*64) + l)*8 + j  (16B/lane contiguous).
#define B1N 81920   // K=640: train k 0..499, zero 500..511, agg 512..639; N=128
#define B2N 32768   // K=256: h1 (W2s) 0..127, agg (W2n) 128..255; N=128
#define B3N 16384   // K=128 Wc1, N=128
#define B4N 2048    // K=128 Wc2, N=16
__global__ void k_pack(const float* __restrict__ W1n, const float* __restrict__ W1s,
                       const float* __restrict__ W2n, const float* __restrict__ W2s,
                       const float* __restrict__ Wc1, const float* __restrict__ Wc2,
                       u16* __restrict__ B1h, u16* __restrict__ B1l,
                       u16* __restrict__ B2h, u16* __restrict__ B2l,
                       u16* __restrict__ B3h, u16* __restrict__ B3l,
                       u16* __restrict__ B4h, u16* __restrict__ B4l) {
    int idx = blockIdx.x * 256 + threadIdx.x;
    float v = 0.f;
    u16 *ph = 0, *pl = 0;
    int off = 0;
    if (idx < B1N) {
        int j = idx & 7, l = (idx >> 3) & 63, rest = idx >> 9;
        int g = rest & 7, kk = rest >> 3;
        int k = kk * 32 + ((l >> 4) << 3) + j, n = (g << 4) + (l & 15);
        if (k < 500) v = W1s[k * 128 + n];
        else if (k >= 512) v = W1n[(k - 512) * 128 + n];
        ph = B1h; pl = B1l; off = idx;
    } else if (idx < B1N + B2N) {
        int e = idx - B1N;
        int j = e & 7, l = (e >> 3) & 63, rest = e >> 9;
        int g = rest & 7, kk = rest >> 3;
        int k = kk * 32 + ((l >> 4) << 3) + j, n = (g << 4) + (l & 15);
        v = (k < 128) ? W2s[k * 128 + n] : W2n[(k - 128) * 128 + n];
        ph = B2h; pl = B2l; off = e;
    } else if (idx < B1N + B2N + B3N) {
        int e = idx - (B1N + B2N);
        int j = e & 7, l = (e >> 3) & 63, rest = e >> 9;
        int g = rest & 7, kk = rest >> 3;
        int k = kk * 32 + ((l >> 4) << 3) + j, n = (g << 4) + (l & 15);
        v = Wc1[k * 128 + n];
        ph = B3h; pl = B3l; off = e;
    } else if (idx < B1N + B2N + B3N + B4N) {
        int e = idx - (B1N + B2N + B3N);
        int j = e & 7, l = (e >> 3) & 63, kk = e >> 9;
        int k = kk * 32 + ((l >> 4) << 3) + j, n = l & 15;
        v = Wc2[k * 16 + n];
        ph = B4h; pl = B4l; off = e;
    }
    if (ph) {
        u16 hi = f2b(v);
        u16 lo = f2b(v - b2f(hi));
        ph[off] = hi;
        pl[off] = lo;
    }
}

// ---- fused 4-layer split-bf16 MFMA kernel ---------------------------------
// Block: 512 thr (8 waves), 32 rows (2 row-tiles of 16).
// wave w: row-tile rt = w&1, col-groups g0 = (w>>1)*2 (2 groups of 16 cols).
// LDS: SAh/SAl 32x648 u16 (stride 648 = 81*16B odd -> only free 2-way alias),
//      S1/S2 hi+lo 32x136 (17*16B odd). Total 117760 B -> 1 block/CU.
__global__ __launch_bounds__(512) void k_mega(
    const float2* __restrict__ tr2, const float2* __restrict__ ag2,
    const u16* __restrict__ B1h, const u16* __restrict__ B1l,
    const u16* __restrict__ B2h, const u16* __restrict__ B2l,
    const u16* __restrict__ B3h, const u16* __restrict__ B3l,
    const u16* __restrict__ B4h, const u16* __restrict__ B4l,
    const float* __restrict__ b1, const float* __restrict__ b2,
    const float* __restrict__ bc1, const float* __restrict__ bc2,
    float* __restrict__ out) {
    __shared__ __align__(16) u16 SAh[32 * 648], SAl[32 * 648];
    __shared__ __align__(16) u16 S1h[32 * 136], S1l[32 * 136];
    __shared__ __align__(16) u16 S2h[32 * 136], S2l[32 * 136];
    int t = threadIdx.x;
    int row0 = blockIdx.x * 32;

    // stage A: split fp32 -> (hi,lo) bf16 pairs, packed as u32
    u32* SAh32 = (u32*)SAh;
    u32* SAl32 = (u32*)SAl;
    for (int i = t; i < 32 * 256; i += 512) {  // train cols (float2 idx 0..255)
        int r = i >> 8, c2 = i & 255;
        float2 v = {0.f, 0.f};
        if (c2 < 250) v = tr2[(size_t)(row0 + r) * 250 + c2];
        u16 hx = f2b(v.x), hy = f2b(v.y);
        u16 lx = f2b(v.x - b2f(hx)), ly = f2b(v.y - b2f(hy));
        SAh32[r * 324 + c2] = (u32)hx | ((u32)hy << 16);
        SAl32[r * 324 + c2] = (u32)lx | ((u32)ly << 16);
    }
    for (int i = t; i < 32 * 64; i += 512) {   // agg region k 512..639
        int r = i >> 6, c2 = i & 63;
        float2 v = ag2[(size_t)(row0 + r) * 64 + c2];
        u16 hx = f2b(v.x), hy = f2b(v.y);
        u16 lx = f2b(v.x - b2f(hx)), ly = f2b(v.y - b2f(hy));
        SAh32[r * 324 + 256 + c2] = (u32)hx | ((u32)hy << 16);
        SAl32[r * 324 + 256 + c2] = (u32)lx | ((u32)ly << 16);
    }
    __syncthreads();

    int lane = t & 63, wave = t >> 6;
    int m = lane & 15, q = lane >> 4, n16 = lane & 15;
    int rt = wave & 1, g0 = (wave >> 1) * 2;
    int arow = (rt * 16 + m) * 648 + q * 8;
    int hrow = (rt * 16 + m) * 136 + q * 8;
    int crow = rt * 16 + q * 4;
    const f32x4 z4 = {0.f, 0.f, 0.f, 0.f};

    f32x4 acc[2];

    // ---- layer1: h1 = relu([train|agg] @ W1 + b1), K=640 ----
    acc[0] = z4; acc[1] = z4;
    for (int kk = 0; kk < 20; ++kk) {
        bf16x8 ah = *(const bf16x8*)(SAh + arow + kk * 32);
        bf16x8 al = *(const bf16x8*)(SAl + arow + kk * 32);
#pragma unroll
        for (int gg = 0; gg < 2; ++gg) {
            size_t bo = ((size_t)(kk * 8 + g0 + gg) * 64 + lane) * 8;
            bf16x8 bh = *(const bf16x8*)(B1h + bo);
            bf16x8 bl = *(const bf16x8*)(B1l + bo);
            acc[gg] = __builtin_amdgcn_mfma_f32_16x16x32_bf16(ah, bh, acc[gg], 0, 0, 0);
            acc[gg] = __builtin_amdgcn_mfma_f32_16x16x32_bf16(ah, bl, acc[gg], 0, 0, 0);
            acc[gg] = __builtin_amdgcn_mfma_f32_16x16x32_bf16(al, bh, acc[gg], 0, 0, 0);
        }
    }
#pragma unroll
    for (int gg = 0; gg < 2; ++gg) {
        int n = (g0 + gg) * 16 + n16;
        float bias = b1[n];
#pragma unroll
        for (int rg = 0; rg < 4; ++rg) {
            float v = acc[gg][rg] + bias;
            v = v > 0.f ? v : 0.f;
            u16 hi = f2b(v), lo = f2b(v - b2f(hi));
            int ix = (crow + rg) * 136 + n;
            S1h[ix] = hi; S1l[ix] = lo;
        }
    }
    __syncthreads();

    // ---- layer2: h2 = relu([h1|agg] @ W2 + b2), K=256 ----
    acc[0] = z4; acc[1] = z4;
    for (int kk = 0; kk < 8; ++kk) {
        bf16x8 ah, al;
        if (kk < 4) {
            ah = *(const bf16x8*)(S1h + hrow + kk * 32);
            al = *(const bf16x8*)(S1l + hrow + kk * 32);
        } else {
            ah = *(const bf16x8*)(SAh + arow + 512 + (kk - 4) * 32);
            al = *(const bf16x8*)(SAl + arow + 512 + (kk - 4) * 32);
        }
#pragma unroll
        for (int gg = 0; gg < 2; ++gg) {
            size_t bo = ((size_t)(kk * 8 + g0 + gg) * 64 + lane) * 8;
            bf16x8 bh = *(const bf16x8*)(B2h + bo);
            bf16x8 bl = *(const bf16x8*)(B2l + bo);
            acc[gg] = __builtin_amdgcn_mfma_f32_16x16x32_bf16(ah, bh, acc[gg], 0, 0, 0);
            acc[gg] = __builtin_amdgcn_mfma_f32_16x16x32_bf16(ah, bl, acc[gg], 0, 0, 0);
            acc[gg] = __builtin_amdgcn_mfma_f32_16x16x32_bf16(al, bh, acc[gg], 0, 0, 0);
        }
    }
#pragma unroll
    for (int gg = 0; gg < 2; ++gg) {
        int n = (g0 + gg) * 16 + n16;
        float bias = b2[n];
#pragma unroll
        for (int rg = 0; rg < 4; ++rg) {
            float v = acc[gg][rg] + bias;
            v = v > 0.f ? v : 0.f;
            u16 hi = f2b(v), lo = f2b(v - b2f(hi));
            int ix = (crow + rg) * 136 + n;
            S2h[ix] = hi; S2l[ix] = lo;
        }
    }
    __syncthreads();

    // ---- layer3: h3 = relu(h2 @ Wc1 + bc1), K=128 (write back to S1) ----
    acc[0] = z4; acc[1] = z4;
    for (int kk = 0; kk < 4; ++kk) {
        bf16x8 ah = *(const bf16x8*)(S2h + hrow + kk * 32);
        bf16x8 al = *(const bf16x8*)(S2l + hrow + kk * 32);
#pragma unroll
        for (int gg = 0; gg < 2; ++gg) {
            size_t bo = ((size_t)(kk * 8 + g0 + gg) * 64 + lane) * 8;
            bf16x8 bh = *(const bf16x8*)(B3h + bo);
            bf16x8 bl = *(const bf16x8*)(B3l + bo);
            acc[gg] = __builtin_amdgcn_mfma_f32_16x16x32_bf16(ah, bh, acc[gg], 0, 0, 0);
            acc[gg] = __builtin_amdgcn_mfma_f32_16x16x32_bf16(ah, bl, acc[gg], 0, 0, 0);
            acc[gg] = __builtin_amdgcn_mfma_f32_16x16x32_bf16(al, bh, acc[gg], 0, 0, 0);
        }
    }
#pragma unroll
    for (int gg = 0; gg < 2; ++gg) {
        int n = (g0 + gg) * 16 + n16;
        float bias = bc1[n];
#pragma unroll
        for (int rg = 0; rg < 4; ++rg) {
            float v = acc[gg][rg] + bias;
            v = v > 0.f ? v : 0.f;
            u16 hi = f2b(v), lo = f2b(v - b2f(hi));
            int ix = (crow + rg) * 136 + n;
            S1h[ix] = hi; S1l[ix] = lo;
        }
    }
    __syncthreads();

    // ---- layer4: out = h3 @ Wc2 + bc2, K=128, N=16 (waves 0,1 only) ----
    if ((wave >> 1) == 0) {
        f32x4 a4 = z4;
        for (int kk = 0; kk < 4; ++kk) {
            bf16x8 ah = *(const bf16x8*)(S1h + hrow + kk * 32);
            bf16x8 al = *(const bf16x8*)(S1l + hrow + kk * 32);
            size_t bo = ((size_t)kk * 64 + lane) * 8;
            bf16x8 bh = *(const bf16x8*)(B4h + bo);
            bf16x8 bl = *(const bf16x8*)(B4l + bo);
            a4 = __builtin_amdgcn_mfma_f32_16x16x32_bf16(ah, bh, a4, 0, 0, 0);
            a4 = __builtin_amdgcn_mfma_f32_16x16x32_bf16(ah, bl, a4, 0, 0, 0);
            a4 = __builtin_amdgcn_mfma_f32_16x16x32_bf16(al, bh, a4, 0, 0, 0);
        }
        float bias = bc2[n16];
#pragma unroll
        for (int rg = 0; rg < 4; ++rg)
            out[(size_t)(row0 + crow + rg) * NCLS + n16] = a4[rg] + bias;
    }
}

extern "C" void kernel_launch(void* const* d_in, const int* in_sizes, int n_in,
                              void* d_out, int out_size, void* d_ws, size_t ws_size,
                              hipStream_t stream) {
    const float* gene = (const float*)d_in[0];
    const float* train = (const float*)d_in[1];
    const int* esrc = (const int*)d_in[2];
    const int* edst = (const int*)d_in[3];

    char* ws = (char*)d_ws;
    int* cnt = (int*)(ws + 0);             //    80000
    int* rowptr = (int*)(ws + 80000);      //    80004
    int* fill = (int*)(ws + 160064);       //    80000
    int* csr = (int*)(ws + 240064);        //  2560000
    float* agg = (float*)(ws + 2800064);   // 10240000
    u16* B1h = (u16*)(ws + 13040064);      //   163840
    u16* B1l = (u16*)(ws + 13203904);      //   163840
    u16* B2h = (u16*)(ws + 13367744);      //    65536
    u16* B2l = (u16*)(ws + 13433280);      //    65536
    u16* B3h = (u16*)(ws + 13498816);      //    32768
    u16* B3l = (u16*)(ws + 13531584);      //    32768
    u16* B4h = (u16*)(ws + 13564352);      //     4096
    u16* B4l = (u16*)(ws + 13568448);      //     4096
    // total ~13.6 MB

    hipMemsetAsync(cnt, 0, NT * sizeof(int), stream);
    k_count<<<(NE + 255) / 256, 256, 0, stream>>>(edst, cnt);
    k_scan<<<1, 1024, 0, stream>>>(cnt, rowptr, fill);
    k_fill<<<(NE + 255) / 256, 256, 0, stream>>>(esrc, edst, fill, csr);
    k_pack<<<(B1N + B2N + B3N + B4N) / 256, 256, 0, stream>>>(
        (const float*)d_in[4], (const float*)d_in[5], (const float*)d_in[7],
        (const float*)d_in[8], (const float*)d_in[10], (const float*)d_in[12],
        B1h, B1l, B2h, B2l, B3h, B3l, B4h, B4l);
    k_gather<<<NT / 4, 256, 0, stream>>>((const float2*)gene, rowptr, csr,
                                         (float2*)agg);
    k_mega<<<NT / 32, 512, 0, stream>>>(
        (const float2*)train, (const float2*)agg,
        B1h, B1l, B2h, B2l, B3h, B3l, B4h, B4l,
        (const float*)d_in[6], (const float*)d_in[9], (const float*)d_in[11],
        (const float*)d_in[13], (float*)d_out);
}

// Round 7
// 222.335 us; speedup vs baseline: 2.1224x; 1.3073x over previous
//
#include <hip/hip_runtime.h>

// WordSAGE on MI355X — fp32 in/out. Round-7 structure:
//   k_fillpad: padded CSR (cap 96, u16 src idx) in ONE edge pass
//   k_convert: train fp32 -> bf16-hi into AH[20000][640] (k 500..511 zeroed)
//   k_gather : mean-agg gene -> AH[:,512:640] (hi) + AGL (lo)
//   k_pack   : weights -> split hi/lo B-fragment-order buffers
//   k_mega   : fused 4-layer MFMA, A-fragments streamed from global (no LDS
//              A-staging; LDS only for inter-layer h tiles, 34.8 KB)
// Precision: split bf16 (hi+lo) for weights/agg/h; train hi-only
// (error ~0.002 std: |a|*2^-9 * sqrt(K) * 1/sqrt(K) weight scale).

#define NG 2500
#define NT 20000
#define NE 640000
#define NCLS 16
#define CAP 96

typedef unsigned short u16;
typedef unsigned int u32;

typedef float f32x4 __attribute__((ext_vector_type(4)));
typedef __bf16 bf16x8 __attribute__((ext_vector_type(8)));

__device__ __forceinline__ float b2f(u16 u) { return __uint_as_float(((u32)u) << 16); }
__device__ __forceinline__ u16 f2b(float f) {  // RNE fp32->bf16
    u32 u = __float_as_uint(f);
    return (u16)((u + 0x7fffu + ((u >> 16) & 1u)) >> 16);
}

// ---- padded-CSR build: one pass over edges --------------------------------
__global__ void k_fillpad(const int* __restrict__ src, const int* __restrict__ dst,
                          int* __restrict__ cnt, u16* __restrict__ csr) {
    int e = blockIdx.x * 256 + threadIdx.x;
    if (e < NE) {
        unsigned d = (unsigned)dst[e];
        if (d < NT) {
            int slot = atomicAdd(&cnt[d], 1);
            if (slot < CAP) csr[d * CAP + slot] = (u16)src[e];
        }
    }
}

// ---- train fp32 -> bf16 hi, AH row-major [NT][640] ------------------------
__global__ __launch_bounds__(256) void k_convert(const float2* __restrict__ tr2,
                                                 u32* __restrict__ AH32) {
    int r = blockIdx.x;       // row
    int c = threadIdx.x;      // u32 col 0..255 (= u16 cols 0..511)
    float2 v = {0.f, 0.f};
    if (c < 250) v = tr2[(size_t)r * 250 + c];
    AH32[(size_t)r * 320 + c] = (u32)f2b(v.x) | ((u32)f2b(v.y) << 16);
}

// ---- gather-mean -> AH agg region (hi) + AGL (lo) -------------------------
__global__ __launch_bounds__(256) void k_gather(const float2* __restrict__ g2,
                                                const int* __restrict__ cnt,
                                                const u16* __restrict__ csr,
                                                u32* __restrict__ AH32,
                                                u32* __restrict__ AGL32) {
    int wave = threadIdx.x >> 6, lane = threadIdx.x & 63;
    int d = blockIdx.x * 4 + wave;
    int c = cnt[d];
    if (c > CAP) c = CAP;
    const u16* row = csr + d * CAP;
    float a0 = 0.f, a1 = 0.f, c0 = 0.f, c1 = 0.f;
    int j = 0;
    for (; j + 1 < c; j += 2) {
        int s0 = row[j], s1 = row[j + 1];
        float2 v0 = g2[(size_t)s0 * 64 + lane];
        float2 v1 = g2[(size_t)s1 * 64 + lane];
        a0 += v0.x; a1 += v0.y;
        c0 += v1.x; c1 += v1.y;
    }
    if (j < c) {
        int s = row[j];
        float2 v = g2[(size_t)s * 64 + lane];
        a0 += v.x; a1 += v.y;
    }
    float inv = (c > 0) ? 1.f / (float)c : 0.f;
    float x = (a0 + c0) * inv, y = (a1 + c1) * inv;
    u16 hx = f2b(x), hy = f2b(y);
    u16 lx = f2b(x - b2f(hx)), ly = f2b(y - b2f(hy));
    AH32[(size_t)d * 320 + 256 + lane] = (u32)hx | ((u32)hy << 16);
    AGL32[(size_t)d * 64 + lane] = (u32)lx | ((u32)ly << 16);
}

// ---- pack fp32 weights into split hi/lo bf16 B-fragment buffers -----------
// B-frag (16x16x32): lane l holds B[k = kk*32 + (l>>4)*8 + j][n = g*16 + (l&15)],
// memory idx = (((kk*gN + g)*64) + l)*8 + j  (16B/lane contiguous).
#define B1N 81920   // K=640: train k 0..499, zero 500..511, agg 512..639; N=128
#define B2N 32768   // K=256: h1 (W2s) 0..127, agg (W2n) 128..255; N=128
#define B3N 16384   // K=128 Wc1, N=128
#define B4N 2048    // K=128 Wc2, N=16
__global__ void k_pack(const float* __restrict__ W1n, const float* __restrict__ W1s,
                       const float* __restrict__ W2n, const float* __restrict__ W2s,
                       const float* __restrict__ Wc1, const float* __restrict__ Wc2,
                       u16* __restrict__ B1h, u16* __restrict__ B1l,
                       u16* __restrict__ B2h, u16* __restrict__ B2l,
                       u16* __restrict__ B3h, u16* __restrict__ B3l,
                       u16* __restrict__ B4h, u16* __restrict__ B4l) {
    int idx = blockIdx.x * 256 + threadIdx.x;
    float v = 0.f;
    u16 *ph = 0, *pl = 0;
    int off = 0;
    if (idx < B1N) {
        int j = idx & 7, l = (idx >> 3) & 63, rest = idx >> 9;
        int g = rest & 7, kk = rest >> 3;
        int k = kk * 32 + ((l >> 4) << 3) + j, n = (g << 4) + (l & 15);
        if (k < 500) v = W1s[k * 128 + n];
        else if (k >= 512) v = W1n[(k - 512) * 128 + n];
        ph = B1h; pl = B1l; off = idx;
    } else if (idx < B1N + B2N) {
        int e = idx - B1N;
        int j = e & 7, l = (e >> 3) & 63, rest = e >> 9;
        int g = rest & 7, kk = rest >> 3;
        int k = kk * 32 + ((l >> 4) << 3) + j, n = (g << 4) + (l & 15);
        v = (k < 128) ? W2s[k * 128 + n] : W2n[(k - 128) * 128 + n];
        ph = B2h; pl = B2l; off = e;
    } else if (idx < B1N + B2N + B3N) {
        int e = idx - (B1N + B2N);
        int j = e & 7, l = (e >> 3) & 63, rest = e >> 9;
        int g = rest & 7, kk = rest >> 3;
        int k = kk * 32 + ((l >> 4) << 3) + j, n = (g << 4) + (l & 15);
        v = Wc1[k * 128 + n];
        ph = B3h; pl = B3l; off = e;
    } else if (idx < B1N + B2N + B3N + B4N) {
        int e = idx - (B1N + B2N + B3N);
        int j = e & 7, l = (e >> 3) & 63, kk = e >> 9;
        int k = kk * 32 + ((l >> 4) << 3) + j, n = l & 15;
        v = Wc2[k * 16 + n];
        ph = B4h; pl = B4l; off = e;
    }
    if (ph) {
        u16 hi = f2b(v);
        u16 lo = f2b(v - b2f(hi));
        ph[off] = hi;
        pl[off] = lo;
    }
}

// ---- fused 4-layer MFMA kernel, A streamed from global --------------------
// Block: 512 thr (8 waves), 32 rows. wave = (rt, cw): rt=wave&1 row-tile,
// cw=wave>>1 col-pair (2 col-groups each). LDS: only h tiles (34.8 KB).
__global__ __launch_bounds__(512) void k_mega(
    const u16* __restrict__ AH, const u16* __restrict__ AGL,
    const u16* __restrict__ B1h, const u16* __restrict__ B1l,
    const u16* __restrict__ B2h, const u16* __restrict__ B2l,
    const u16* __restrict__ B3h, const u16* __restrict__ B3l,
    const u16* __restrict__ B4h, const u16* __restrict__ B4l,
    const float* __restrict__ b1, const float* __restrict__ b2,
    const float* __restrict__ bc1, const float* __restrict__ bc2,
    float* __restrict__ out) {
    __shared__ __align__(16) u16 S1h[32 * 136], S1l[32 * 136];
    __shared__ __align__(16) u16 S2h[32 * 136], S2l[32 * 136];
    int t = threadIdx.x;
    int lane = t & 63, wave = t >> 6;
    int rt = wave & 1, cw = wave >> 1;  // cw 0..3
    int g0 = cw * 2;
    int m = lane & 15, q = lane >> 4, n16 = lane & 15;
    int row0 = blockIdx.x * 32;
    int grow = row0 + rt * 16 + m;

    const u16* aRow = AH + (size_t)grow * 640 + q * 8;
    const u16* alRow = AGL + (size_t)grow * 128 + q * 8;
    int hrow = (rt * 16 + m) * 136 + q * 8;
    int crow = rt * 16 + q * 4;
    const f32x4 z4 = {0.f, 0.f, 0.f, 0.f};
    f32x4 acc0 = z4, acc1 = z4;

    // ---- layer1: K=640 (train hi-only kk 0..15; agg hi+lo kk 16..19) ----
#pragma unroll 4
    for (int kk = 0; kk < 16; ++kk) {
        bf16x8 ah = *(const bf16x8*)(aRow + kk * 32);
        size_t bo0 = ((size_t)(kk * 8 + g0) * 64 + lane) * 8;
        bf16x8 bh0 = *(const bf16x8*)(B1h + bo0);
        bf16x8 bl0 = *(const bf16x8*)(B1l + bo0);
        bf16x8 bh1 = *(const bf16x8*)(B1h + bo0 + 512);
        bf16x8 bl1 = *(const bf16x8*)(B1l + bo0 + 512);
        acc0 = __builtin_amdgcn_mfma_f32_16x16x32_bf16(ah, bh0, acc0, 0, 0, 0);
        acc0 = __builtin_amdgcn_mfma_f32_16x16x32_bf16(ah, bl0, acc0, 0, 0, 0);
        acc1 = __builtin_amdgcn_mfma_f32_16x16x32_bf16(ah, bh1, acc1, 0, 0, 0);
        acc1 = __builtin_amdgcn_mfma_f32_16x16x32_bf16(ah, bl1, acc1, 0, 0, 0);
    }
#pragma unroll
    for (int kk = 16; kk < 20; ++kk) {
        bf16x8 ah = *(const bf16x8*)(aRow + kk * 32);
        bf16x8 al = *(const bf16x8*)(alRow + (kk - 16) * 32);
        size_t bo0 = ((size_t)(kk * 8 + g0) * 64 + lane) * 8;
        bf16x8 bh0 = *(const bf16x8*)(B1h + bo0);
        bf16x8 bl0 = *(const bf16x8*)(B1l + bo0);
        bf16x8 bh1 = *(const bf16x8*)(B1h + bo0 + 512);
        bf16x8 bl1 = *(const bf16x8*)(B1l + bo0 + 512);
        acc0 = __builtin_amdgcn_mfma_f32_16x16x32_bf16(ah, bh0, acc0, 0, 0, 0);
        acc0 = __builtin_amdgcn_mfma_f32_16x16x32_bf16(ah, bl0, acc0, 0, 0, 0);
        acc0 = __builtin_amdgcn_mfma_f32_16x16x32_bf16(al, bh0, acc0, 0, 0, 0);
        acc1 = __builtin_amdgcn_mfma_f32_16x16x32_bf16(ah, bh1, acc1, 0, 0, 0);
        acc1 = __builtin_amdgcn_mfma_f32_16x16x32_bf16(ah, bl1, acc1, 0, 0, 0);
        acc1 = __builtin_amdgcn_mfma_f32_16x16x32_bf16(al, bh1, acc1, 0, 0, 0);
    }
    {
        int n0 = g0 * 16 + n16, n1 = n0 + 16;
        float bias0 = b1[n0], bias1 = b1[n1];
#pragma unroll
        for (int rg = 0; rg < 4; ++rg) {
            float v0 = acc0[rg] + bias0; v0 = v0 > 0.f ? v0 : 0.f;
            float v1 = acc1[rg] + bias1; v1 = v1 > 0.f ? v1 : 0.f;
            u16 h0 = f2b(v0), h1v = f2b(v1);
            int ix = (crow + rg) * 136;
            S1h[ix + n0] = h0; S1l[ix + n0] = f2b(v0 - b2f(h0));
            S1h[ix + n1] = h1v; S1l[ix + n1] = f2b(v1 - b2f(h1v));
        }
    }
    __syncthreads();

    // ---- layer2: K=256 (h1 kk 0..3 from LDS; agg kk 4..7 from global) ----
    acc0 = z4; acc1 = z4;
#pragma unroll
    for (int kk = 0; kk < 8; ++kk) {
        bf16x8 ah, al;
        if (kk < 4) {
            ah = *(const bf16x8*)(S1h + hrow + kk * 32);
            al = *(const bf16x8*)(S1l + hrow + kk * 32);
        } else {
            ah = *(const bf16x8*)(aRow + 512 + (kk - 4) * 32);
            al = *(const bf16x8*)(alRow + (kk - 4) * 32);
        }
        size_t bo0 = ((size_t)(kk * 8 + g0) * 64 + lane) * 8;
        bf16x8 bh0 = *(const bf16x8*)(B2h + bo0);
        bf16x8 bl0 = *(const bf16x8*)(B2l + bo0);
        bf16x8 bh1 = *(const bf16x8*)(B2h + bo0 + 512);
        bf16x8 bl1 = *(const bf16x8*)(B2l + bo0 + 512);
        acc0 = __builtin_amdgcn_mfma_f32_16x16x32_bf16(ah, bh0, acc0, 0, 0, 0);
        acc0 = __builtin_amdgcn_mfma_f32_16x16x32_bf16(ah, bl0, acc0, 0, 0, 0);
        acc0 = __builtin_amdgcn_mfma_f32_16x16x32_bf16(al, bh0, acc0, 0, 0, 0);
        acc1 = __builtin_amdgcn_mfma_f32_16x16x32_bf16(ah, bh1, acc1, 0, 0, 0);
        acc1 = __builtin_amdgcn_mfma_f32_16x16x32_bf16(ah, bl1, acc1, 0, 0, 0);
        acc1 = __builtin_amdgcn_mfma_f32_16x16x32_bf16(al, bh1, acc1, 0, 0, 0);
    }
    {
        int n0 = g0 * 16 + n16, n1 = n0 + 16;
        float bias0 = b2[n0], bias1 = b2[n1];
#pragma unroll
        for (int rg = 0; rg < 4; ++rg) {
            float v0 = acc0[rg] + bias0; v0 = v0 > 0.f ? v0 : 0.f;
            float v1 = acc1[rg] + bias1; v1 = v1 > 0.f ? v1 : 0.f;
            u16 h0 = f2b(v0), h1v = f2b(v1);
            int ix = (crow + rg) * 136;
            S2h[ix + n0] = h0; S2l[ix + n0] = f2b(v0 - b2f(h0));
            S2h[ix + n1] = h1v; S2l[ix + n1] = f2b(v1 - b2f(h1v));
        }
    }
    __syncthreads();

    // ---- layer3: K=128 (h2 from LDS) -> S1 ----
    acc0 = z4; acc1 = z4;
#pragma unroll
    for (int kk = 0; kk < 4; ++kk) {
        bf16x8 ah = *(const bf16x8*)(S2h + hrow + kk * 32);
        bf16x8 al = *(const bf16x8*)(S2l + hrow + kk * 32);
        size_t bo0 = ((size_t)(kk * 8 + g0) * 64 + lane) * 8;
        bf16x8 bh0 = *(const bf16x8*)(B3h + bo0);
        bf16x8 bl0 = *(const bf16x8*)(B3l + bo0);
        bf16x8 bh1 = *(const bf16x8*)(B3h + bo0 + 512);
        bf16x8 bl1 = *(const bf16x8*)(B3l + bo0 + 512);
        acc0 = __builtin_amdgcn_mfma_f32_16x16x32_bf16(ah, bh0, acc0, 0, 0, 0);
        acc0 = __builtin_amdgcn_mfma_f32_16x16x32_bf16(ah, bl0, acc0, 0, 0, 0);
        acc0 = __builtin_amdgcn_mfma_f32_16x16x32_bf16(al, bh0, acc0, 0, 0, 0);
        acc1 = __builtin_amdgcn_mfma_f32_16x16x32_bf16(ah, bh1, acc1, 0, 0, 0);
        acc1 = __builtin_amdgcn_mfma_f32_16x16x32_bf16(ah, bl1, acc1, 0, 0, 0);
        acc1 = __builtin_amdgcn_mfma_f32_16x16x32_bf16(al, bh1, acc1, 0, 0, 0);
    }
    {
        int n0 = g0 * 16 + n16, n1 = n0 + 16;
        float bias0 = bc1[n0], bias1 = bc1[n1];
#pragma unroll
        for (int rg = 0; rg < 4; ++rg) {
            float v0 = acc0[rg] + bias0; v0 = v0 > 0.f ? v0 : 0.f;
            float v1 = acc1[rg] + bias1; v1 = v1 > 0.f ? v1 : 0.f;
            u16 h0 = f2b(v0), h1v = f2b(v1);
            int ix = (crow + rg) * 136;
            S1h[ix + n0] = h0; S1l[ix + n0] = f2b(v0 - b2f(h0));
            S1h[ix + n1] = h1v; S1l[ix + n1] = f2b(v1 - b2f(h1v));
        }
    }
    __syncthreads();

    // ---- layer4: K=128, N=16 (cw==0 waves only) ----
    if (cw == 0) {
        f32x4 a4 = z4;
#pragma unroll
        for (int kk = 0; kk < 4; ++kk) {
            bf16x8 ah = *(const bf16x8*)(S1h + hrow + kk * 32);
            bf16x8 al = *(const bf16x8*)(S1l + hrow + kk * 32);
            size_t bo = ((size_t)kk * 64 + lane) * 8;
            bf16x8 bh = *(const bf16x8*)(B4h + bo);
            bf16x8 bl = *(const bf16x8*)(B4l + bo);
            a4 = __builtin_amdgcn_mfma_f32_16x16x32_bf16(ah, bh, a4, 0, 0, 0);
            a4 = __builtin_amdgcn_mfma_f32_16x16x32_bf16(ah, bl, a4, 0, 0, 0);
            a4 = __builtin_amdgcn_mfma_f32_16x16x32_bf16(al, bh, a4, 0, 0, 0);
        }
        float bias = bc2[n16];
#pragma unroll
        for (int rg = 0; rg < 4; ++rg)
            out[(size_t)(row0 + crow + rg) * NCLS + n16] = a4[rg] + bias;
    }
}

extern "C" void kernel_launch(void* const* d_in, const int* in_sizes, int n_in,
                              void* d_out, int out_size, void* d_ws, size_t ws_size,
                              hipStream_t stream) {
    const float* gene = (const float*)d_in[0];
    const float* train = (const float*)d_in[1];
    const int* esrc = (const int*)d_in[2];
    const int* edst = (const int*)d_in[3];

    char* ws = (char*)d_ws;
    int* cnt = (int*)(ws + 0);              //    80000
    u16* csr = (u16*)(ws + 80000);          //  3840000
    u16* AH = (u16*)(ws + 3920000);         // 25600000
    u16* AGL = (u16*)(ws + 29520000);       //  5120000
    u16* B1h = (u16*)(ws + 34640000);       //   163840
    u16* B1l = (u16*)(ws + 34803840);       //   163840
    u16* B2h = (u16*)(ws + 34967680);       //    65536
    u16* B2l = (u16*)(ws + 35033216);       //    65536
    u16* B3h = (u16*)(ws + 35098752);       //    32768
    u16* B3l = (u16*)(ws + 35131520);       //    32768
    u16* B4h = (u16*)(ws + 35164288);       //     4096
    u16* B4l = (u16*)(ws + 35168384);       //     4096
    // total 35,172,480 B (within proven ws envelope)

    hipMemsetAsync(cnt, 0, NT * sizeof(int), stream);
    k_fillpad<<<(NE + 255) / 256, 256, 0, stream>>>(esrc, edst, cnt, csr);
    k_convert<<<NT, 256, 0, stream>>>((const float2*)train, (u32*)AH);
    k_pack<<<(B1N + B2N + B3N + B4N) / 256, 256, 0, stream>>>(
        (const float*)d_in[4], (const float*)d_in[5], (const float*)d_in[7],
        (const float*)d_in[8], (const float*)d_in[10], (const float*)d_in[12],
        B1h, B1l, B2h, B2l, B3h, B3l, B4h, B4l);
    k_gather<<<NT / 4, 256, 0, stream>>>((const float2*)gene, cnt, csr,
                                         (u32*)AH, (u32*)AGL);
    k_mega<<<NT / 32, 512, 0, stream>>>(
        AH, AGL, B1h, B1l, B2h, B2l, B3h, B3l, B4h, B4l,
        (const float*)d_in[6], (const float*)d_in[9], (const float*)d_in[11],
        (const float*)d_in[13], (float*)d_out);
}